// Round 5
// baseline (12838.631 us; speedup 1.0000x reference)
//
#include <hip/hip_runtime.h>
#include <math.h>

// B=64, S=128, E=512, H=512, A=256, V=8192, T=32
#define BB 64
#define SS 128
#define EE 512
#define HH 512
#define AA 256
#define VV 8192
#define TT 32

#define NBLK 256
#define NTHR 256

typedef __bf16 bf16x8 __attribute__((ext_vector_type(8)));
typedef float  f32x4  __attribute__((ext_vector_type(4)));

__device__ __forceinline__ bf16x8 cvt_v(float4 u, float4 v) {
    bf16x8 r;
    r[0] = (__bf16)u.x; r[1] = (__bf16)u.y; r[2] = (__bf16)u.z; r[3] = (__bf16)u.w;
    r[4] = (__bf16)v.x; r[5] = (__bf16)v.y; r[6] = (__bf16)v.z; r[7] = (__bf16)v.w;
    return r;
}

#define LDW(d, p) { const float4* q_ = (const float4*)(p); d##0 = q_[0]; d##1 = q_[1]; d##2 = q_[2]; d##3 = q_[3]; }

// ---------------------------------------------------------------------------
// Shared memory union: attention phase vs GEMM phase
// ---------------------------------------------------------------------------
union SMem {
    struct {
        float sh[512];
        float sdec[256];
        float sv[256];
        float sw[128];
        float st[128];
    } a;
    struct {
        __bf16 Bs[2][64][72];   // 18,432 B
        float  Cf[64][68];      // 17,408 B (gates epilogue only)
    } g;
};

// ---------------------------------------------------------------------------
// Device-scope grid barrier (all NBLK blocks co-resident by construction).
// ---------------------------------------------------------------------------
__device__ __forceinline__ void grid_barrier(unsigned* cnt, unsigned* gen) {
    __syncthreads();
    if (threadIdx.x == 0) {
        __threadfence();
        unsigned g = __hip_atomic_load(gen, __ATOMIC_RELAXED, __HIP_MEMORY_SCOPE_AGENT);
        unsigned a = __hip_atomic_fetch_add(cnt, 1u, __ATOMIC_ACQ_REL, __HIP_MEMORY_SCOPE_AGENT);
        if (a == NBLK - 1) {
            __hip_atomic_store(cnt, 0u, __ATOMIC_RELAXED, __HIP_MEMORY_SCOPE_AGENT);
            __hip_atomic_fetch_add(gen, 1u, __ATOMIC_RELEASE, __HIP_MEMORY_SCOPE_AGENT);
        } else {
            while (__hip_atomic_load(gen, __ATOMIC_ACQUIRE, __HIP_MEMORY_SCOPE_AGENT) == g)
                __builtin_amdgcn_s_sleep(2);
        }
        __threadfence();
    }
    __syncthreads();
}

// ---------------------------------------------------------------------------
// Attention for batch b (256 threads): dec proj + scores + softmax + ctx + emb.
// Writes xh[b] = [ctx(512) | emb(512)] bf16.
// ---------------------------------------------------------------------------
__device__ void attn_dev(SMem* sm, int b, int t,
                         const float* __restrict__ encf, const float* __restrict__ encp,
                         const float* __restrict__ W_dec, const float* __restrict__ b_att,
                         const float* __restrict__ v_att, const float* __restrict__ emb,
                         const int* __restrict__ tgt, const float* __restrict__ hbuf,
                         __bf16* __restrict__ xh) {
    const int tid = threadIdx.x;
    sm->a.sh[tid]       = hbuf[b * 512 + tid];
    sm->a.sh[256 + tid] = hbuf[b * 512 + 256 + tid];
    sm->a.sv[tid] = v_att[tid];
    __syncthreads();

    // dec[a] = b_att[a] + sum_k h[k] * W_dec[k,a], a = tid
    {
        float s = b_att[tid];
        const float* w = W_dec + tid;
#pragma unroll 8
        for (int k = 0; k < 512; ++k) s += sm->a.sh[k] * w[(size_t)k * 256];
        sm->a.sdec[tid] = s;
    }
    __syncthreads();

    // scores: wave wv covers s in [wv*32, wv*32+32)
    const int wv = tid >> 6, lane = tid & 63;
    for (int i = 0; i < 32; ++i) {
        const int s = wv * 32 + i;
        const float* ep = encp + ((size_t)b * 128 + s) * 256;
        float sum = 0.f;
#pragma unroll
        for (int c = 0; c < 4; ++c) {
            int a = lane + 64 * c;
            sum += tanhf(ep[a] + sm->a.sdec[a]) * sm->a.sv[a];
        }
#pragma unroll
        for (int off = 32; off > 0; off >>= 1) sum += __shfl_down(sum, off);
        if (lane == 0) sm->a.sw[s] = sum;
    }
    __syncthreads();

    // softmax
    if (tid < 128) sm->a.st[tid] = sm->a.sw[tid];
    __syncthreads();
    for (int off = 64; off > 0; off >>= 1) {
        if (tid < off) sm->a.st[tid] = fmaxf(sm->a.st[tid], sm->a.st[tid + off]);
        __syncthreads();
    }
    const float mx = sm->a.st[0];
    __syncthreads();
    if (tid < 128) { float e = expf(sm->a.sw[tid] - mx); sm->a.sw[tid] = e; sm->a.st[tid] = e; }
    __syncthreads();
    for (int off = 64; off > 0; off >>= 1) {
        if (tid < off) sm->a.st[tid] += sm->a.st[tid + off];
        __syncthreads();
    }
    const float inv = 1.f / sm->a.st[0];

    // ctx: e = tid and tid+256
    float c0 = 0.f, c1 = 0.f;
    const float* ef = encf + (size_t)b * (SS * EE);
#pragma unroll 4
    for (int s = 0; s < 128; ++s) {
        const float w = sm->a.sw[s];
        c0 += w * ef[(size_t)s * 512 + tid];
        c1 += w * ef[(size_t)s * 512 + 256 + tid];
    }
    __bf16* xr = xh + (size_t)b * 1024;
    xr[tid]       = (__bf16)(c0 * inv);
    xr[256 + tid] = (__bf16)(c1 * inv);
    const int tok = (t == 0) ? 0 : tgt[b * TT + t - 1];
    xr[512 + tid] = (__bf16)emb[(size_t)tok * 512 + tid];
    xr[768 + tid] = (__bf16)emb[(size_t)tok * 512 + 256 + tid];
}

// ---------------------------------------------------------------------------
// Logits GEMM tile (64 cols of V): out[:,t,n0:n0+64] = [h|ctx] @ W_out^T + b_out
// K=1024, BK=64 pipelined (R3-validated body).
// ---------------------------------------------------------------------------
__device__ void out_dev(SMem* sm, int n0, int t,
                        const __bf16* __restrict__ hA, const __bf16* __restrict__ xA,
                        const float* __restrict__ W_out, const float* __restrict__ b_out,
                        float* __restrict__ out) {
    const int tid = threadIdx.x;
    const int wv = tid >> 6, lane = tid & 63;
    const int quad = lane >> 4, l16 = lane & 15;
    const int row = tid >> 2, cq = tid & 3;
    const float* bsrc = W_out + (size_t)(n0 + row) * 1024 + cq * 16;
    const __bf16* aHp = hA + (size_t)(wv * 16 + l16) * 512 + quad * 8;
    const __bf16* aXp = xA + (size_t)(wv * 16 + l16) * 1024 + quad * 8;

    f32x4 acc[4] = {{0,0,0,0},{0,0,0,0},{0,0,0,0},{0,0,0,0}};
    float4 wA0, wA1, wA2, wA3, wB0, wB1, wB2, wB3;
    LDW(wA, bsrc); LDW(wB, bsrc + 64);
    bf16x8 aC0 = *(const bf16x8*)aHp, aC1 = *(const bf16x8*)(aHp + 32);
    bf16x8 aN0, aN1;

    for (int it = 0; it < 16; ++it) {
        __bf16* dst = &sm->g.Bs[it & 1][row][cq * 16];
        *(bf16x8*)dst       = cvt_v(wA0, wA1);
        *(bf16x8*)(dst + 8) = cvt_v(wA2, wA3);
        __syncthreads();
        wA0 = wB0; wA1 = wB1; wA2 = wB2; wA3 = wB3;
        if (it + 2 < 16) LDW(wB, bsrc + (it + 2) * 64);
        if (it + 1 < 16) {
            const int itn = it + 1;
            const __bf16* ap = (itn < 8) ? (aHp + itn * 64) : (aXp + (itn - 8) * 64);
            aN0 = *(const bf16x8*)ap; aN1 = *(const bf16x8*)(ap + 32);
        }
#pragma unroll
        for (int c = 0; c < 4; ++c) {
            bf16x8 b0 = *(const bf16x8*)&sm->g.Bs[it & 1][c * 16 + l16][quad * 8];
            bf16x8 b1 = *(const bf16x8*)&sm->g.Bs[it & 1][c * 16 + l16][quad * 8 + 32];
            acc[c] = __builtin_amdgcn_mfma_f32_16x16x32_bf16(aC0, b0, acc[c], 0, 0, 0);
            acc[c] = __builtin_amdgcn_mfma_f32_16x16x32_bf16(aC1, b1, acc[c], 0, 0, 0);
        }
        aC0 = aN0; aC1 = aN1;
        __syncthreads();
    }

    const int m = wv * 16 + quad * 4;
    const int nb = n0 + l16;
    float* op = out + (size_t)t * VV + nb;
#pragma unroll
    for (int r = 0; r < 4; ++r) {
        float* orow = op + (size_t)(m + r) * (TT * VV);
        orow[ 0] = acc[0][r] + b_out[nb +  0];
        orow[16] = acc[1][r] + b_out[nb + 16];
        orow[32] = acc[2][r] + b_out[nb + 32];
        orow[48] = acc[3][r] + b_out[nb + 48];
    }
}

// ---------------------------------------------------------------------------
// Gates GEMM tile + fused LSTM (R3-validated body). n0 = bid*64 of 2048 cols
// (permuted: col n <-> orig gate row (n&3)*512+(n>>2)). K=1536=[h|ctx|emb].
// ---------------------------------------------------------------------------
__device__ void gates_dev(SMem* sm, int n0,
                          const __bf16* __restrict__ h_old, const __bf16* __restrict__ xh,
                          const float* __restrict__ W_ih, const float* __restrict__ W_hh,
                          const float* __restrict__ b_ih, const float* __restrict__ b_hh,
                          float* __restrict__ hbuf, float* __restrict__ cbuf,
                          __bf16* __restrict__ h_new) {
    const int tid = threadIdx.x;
    const int wv = tid >> 6, lane = tid & 63;
    const int quad = lane >> 4, l16 = lane & 15;
    const int row = tid >> 2, cq = tid & 3;
    const int nglob = n0 + row;
    const int j = ((nglob & 3) << 9) + (nglob >> 2);
    const float* rH = W_hh + (size_t)j * 512;
    const float* rI = W_ih + (size_t)j * 1024;
    const __bf16* aHp = h_old + (size_t)(wv * 16 + l16) * 512 + quad * 8;
    const __bf16* aXp = xh + (size_t)(wv * 16 + l16) * 1024 + quad * 8;

    f32x4 acc[4] = {{0,0,0,0},{0,0,0,0},{0,0,0,0},{0,0,0,0}};

    auto wsrc = [&](int it) -> const float* {
        const int k = it * 64 + cq * 16;
        if (k < 512)  return rH + k;
        if (k < 1024) return rI + k;
        return rI + (k - 1024);
    };
    float4 wA0, wA1, wA2, wA3, wB0, wB1, wB2, wB3;
    LDW(wA, wsrc(0)); LDW(wB, wsrc(1));
    bf16x8 aC0 = *(const bf16x8*)aHp, aC1 = *(const bf16x8*)(aHp + 32);
    bf16x8 aN0, aN1;

    for (int it = 0; it < 24; ++it) {
        __bf16* dst = &sm->g.Bs[it & 1][row][cq * 16];
        *(bf16x8*)dst       = cvt_v(wA0, wA1);
        *(bf16x8*)(dst + 8) = cvt_v(wA2, wA3);
        __syncthreads();
        wA0 = wB0; wA1 = wB1; wA2 = wB2; wA3 = wB3;
        if (it + 2 < 24) LDW(wB, wsrc(it + 2));
        if (it + 1 < 24) {
            const int itn = it + 1;
            const __bf16* ap = (itn < 8) ? (aHp + itn * 64) : (aXp + (itn - 8) * 64);
            aN0 = *(const bf16x8*)ap; aN1 = *(const bf16x8*)(ap + 32);
        }
#pragma unroll
        for (int c = 0; c < 4; ++c) {
            bf16x8 b0 = *(const bf16x8*)&sm->g.Bs[it & 1][c * 16 + l16][quad * 8];
            bf16x8 b1 = *(const bf16x8*)&sm->g.Bs[it & 1][c * 16 + l16][quad * 8 + 32];
            acc[c] = __builtin_amdgcn_mfma_f32_16x16x32_bf16(aC0, b0, acc[c], 0, 0, 0);
            acc[c] = __builtin_amdgcn_mfma_f32_16x16x32_bf16(aC1, b1, acc[c], 0, 0, 0);
        }
        aC0 = aN0; aC1 = aN1;
        __syncthreads();
    }

#pragma unroll
    for (int r = 0; r < 4; ++r) {
        sm->g.Cf[wv * 16 + quad * 4 + r][ 0 + l16] = acc[0][r];
        sm->g.Cf[wv * 16 + quad * 4 + r][16 + l16] = acc[1][r];
        sm->g.Cf[wv * 16 + quad * 4 + r][32 + l16] = acc[2][r];
        sm->g.Cf[wv * 16 + quad * 4 + r][48 + l16] = acc[3][r];
    }
    __syncthreads();
    const int U0 = n0 >> 2;
    for (int it = tid; it < 1024; it += 256) {
        const int bb = it >> 4, ul = it & 15;
        const int ug = U0 + ul;
        const float gi = sm->g.Cf[bb][4 * ul + 0] + b_ih[ug]        + b_hh[ug];
        const float gf = sm->g.Cf[bb][4 * ul + 1] + b_ih[512 + ug]  + b_hh[512 + ug];
        const float gg = sm->g.Cf[bb][4 * ul + 2] + b_ih[1024 + ug] + b_hh[1024 + ug];
        const float go = sm->g.Cf[bb][4 * ul + 3] + b_ih[1536 + ug] + b_hh[1536 + ug];
        const float si = 1.f / (1.f + expf(-gi));
        const float sf = 1.f / (1.f + expf(-gf));
        const float so = 1.f / (1.f + expf(-go));
        const float cn = sf * cbuf[bb * 512 + ug] + si * tanhf(gg);
        const float hn = so * tanhf(cn);
        cbuf[bb * 512 + ug] = cn;
        hbuf[bb * 512 + ug] = hn;
        h_new[(size_t)bb * 512 + ug] = (__bf16)hn;
    }
}

// ---------------------------------------------------------------------------
// Persistent megakernel: 32 decode steps, 2 grid barriers per step.
// blocks 0-63: attention(t). blocks 64-191: logits GEMM(t-1). blocks 0-31: gates(t).
// ---------------------------------------------------------------------------
__global__ __launch_bounds__(NTHR) void megakernel(
    const float* __restrict__ encf, const float* __restrict__ encp,
    const float* __restrict__ W_dec, const float* __restrict__ b_att,
    const float* __restrict__ v_att, const float* __restrict__ emb,
    const int* __restrict__ tgt,
    const float* __restrict__ W_ih, const float* __restrict__ W_hh,
    const float* __restrict__ b_ih, const float* __restrict__ b_hh,
    const float* __restrict__ W_out, const float* __restrict__ b_out,
    unsigned* __restrict__ bar,          // [cnt, gen] zeroed by memset
    float* __restrict__ hbuf, float* __restrict__ cbuf,
    __bf16* __restrict__ hb0, __bf16* __restrict__ hb1,   // hb1 zeroed (h_old at t=0)
    __bf16* __restrict__ x0, __bf16* __restrict__ x1,
    float* __restrict__ out)
{
    __shared__ SMem sm;
    const int bid = blockIdx.x;
    unsigned* cnt = bar;
    unsigned* gen = bar + 1;

    for (int t = 0; t < TT; ++t) {
        __bf16* xh_cur  = (t & 1) ? x1 : x0;
        __bf16* xh_prev = (t & 1) ? x0 : x1;
        __bf16* hb_cur  = (t & 1) ? hb1 : hb0;   // h_new(t)
        __bf16* hb_prev = (t & 1) ? hb0 : hb1;   // h_new(t-1); hb1 zeroed for t=0

        // ---- Phase A: attention(t) || logits(t-1) ----
        if (bid < 64) {
            attn_dev(&sm, bid, t, encf, encp, W_dec, b_att, v_att, emb, tgt, hbuf, xh_cur);
        } else if (bid < 192 && t > 0) {
            out_dev(&sm, (bid - 64) * 64, t - 1, hb_prev, xh_prev, W_out, b_out, out);
        }
        grid_barrier(cnt, gen);

        // ---- Phase B: gates(t) + LSTM ----
        if (bid < 32) {
            gates_dev(&sm, bid * 64, hb_prev, xh_cur, W_ih, W_hh, b_ih, b_hh,
                      hbuf, cbuf, hb_cur);
        }
        grid_barrier(cnt, gen);
    }
    // trailing logits for t=31 (hb_cur = hb1 at t=31? 31&1=1 -> hb1... compute: t=31 odd)
    if (bid >= 64 && bid < 192) {
        out_dev(&sm, (bid - 64) * 64, TT - 1,
                (TT - 1) & 1 ? hb1 : hb0,
                (TT - 1) & 1 ? x1 : x0,
                W_out, b_out, out);
    }
}

// ---------------------------------------------------------------------------
// fp32 GEMM (NN): one-time enc_proj.
// ---------------------------------------------------------------------------
__global__ __launch_bounds__(256) void gemm_nn(
    const float* __restrict__ A, int lda,
    const float* __restrict__ B, int ldb,
    float* __restrict__ C, int ldc, int K)
{
    __shared__ float As[16][68];
    __shared__ float Bs[16][68];
    const int tid = threadIdx.x;
    const int m0 = blockIdx.x * 64, n0 = blockIdx.y * 64;
    const int row = tid >> 2, kq = (tid & 3) * 4;
    const int kk = tid >> 4, nq = (tid & 15) * 4;
    const int tm = tid >> 4, tn = tid & 15;
    float acc[4][4] = {};
    for (int k0 = 0; k0 < K; k0 += 16) {
        float4 av = *(const float4*)(A + (size_t)(m0 + row) * lda + k0 + kq);
        float4 bv = *(const float4*)(B + (size_t)(k0 + kk) * ldb + n0 + nq);
        As[kq + 0][row] = av.x; As[kq + 1][row] = av.y;
        As[kq + 2][row] = av.z; As[kq + 3][row] = av.w;
        *(float4*)&Bs[kk][nq] = bv;
        __syncthreads();
#pragma unroll
        for (int k = 0; k < 16; ++k) {
            float4 a = *(const float4*)&As[k][tm * 4];
            float4 b = *(const float4*)&Bs[k][tn * 4];
            acc[0][0] += a.x * b.x; acc[0][1] += a.x * b.y; acc[0][2] += a.x * b.z; acc[0][3] += a.x * b.w;
            acc[1][0] += a.y * b.x; acc[1][1] += a.y * b.y; acc[1][2] += a.y * b.z; acc[1][3] += a.y * b.w;
            acc[2][0] += a.z * b.x; acc[2][1] += a.z * b.y; acc[2][2] += a.z * b.z; acc[2][3] += a.z * b.w;
            acc[3][0] += a.w * b.x; acc[3][1] += a.w * b.y; acc[3][2] += a.w * b.z; acc[3][3] += a.w * b.w;
        }
        __syncthreads();
    }
#pragma unroll
    for (int i = 0; i < 4; ++i) {
        float4 r = make_float4(acc[i][0], acc[i][1], acc[i][2], acc[i][3]);
        *(float4*)(C + (size_t)(m0 + tm * 4 + i) * ldc + n0 + tn * 4) = r;
    }
}

// ---------------------------------------------------------------------------
extern "C" void kernel_launch(void* const* d_in, const int* in_sizes, int n_in,
                              void* d_out, int out_size, void* d_ws, size_t ws_size,
                              hipStream_t stream)
{
    (void)in_sizes; (void)n_in; (void)out_size; (void)ws_size;
    const float* encf  = (const float*)d_in[0];
    const int*   tgt   = (const int*)  d_in[1];
    const float* emb   = (const float*)d_in[2];
    const float* W_enc = (const float*)d_in[3];
    const float* W_dec = (const float*)d_in[4];
    const float* b_att = (const float*)d_in[5];
    const float* v_att = (const float*)d_in[6];
    const float* W_ih  = (const float*)d_in[7];
    const float* W_hh  = (const float*)d_in[8];
    const float* b_ih  = (const float*)d_in[9];
    const float* b_hh  = (const float*)d_in[10];
    const float* W_out = (const float*)d_in[11];
    const float* b_out = (const float*)d_in[12];
    float* out = (float*)d_out;

    // workspace layout (~8.9 MB). Zero-init region first, contiguous:
    //   [bar(256f) | hbuf(32768f) | cbuf(32768f) | hb1(16384f)]  -> one memset
    float* ws = (float*)d_ws;
    size_t off = 0;
    auto alloc = [&](size_t n) { float* p = ws + off; off += (n + 255) & ~(size_t)255; return p; };
    unsigned* bar  = (unsigned*)alloc(256);
    float*    hbuf = alloc((size_t)BB * HH);
    float*    cbuf = alloc((size_t)BB * HH);
    __bf16*   hb1  = (__bf16*)alloc((size_t)BB * HH / 2);
    const size_t zero_bytes = off * sizeof(float);
    __bf16*   hb0  = (__bf16*)alloc((size_t)BB * HH / 2);
    __bf16*   x0   = (__bf16*)alloc((size_t)BB * 1024 / 2);
    __bf16*   x1   = (__bf16*)alloc((size_t)BB * 1024 / 2);
    float*    encp = alloc((size_t)BB * SS * AA);

    hipMemsetAsync(d_ws, 0, zero_bytes, stream);
    gemm_nn<<<dim3(BB * SS / 64, AA / 64), 256, 0, stream>>>(encf, EE, W_enc, AA, encp, AA, EE);
    megakernel<<<NBLK, NTHR, 0, stream>>>(encf, encp, W_dec, b_att, v_att, emb, tgt,
                                          W_ih, W_hh, b_ih, b_hh, W_out, b_out,
                                          bar, hbuf, cbuf, hb0, hb1, x0, x1, out);
}